// Round 3
// baseline (304.828 us; speedup 1.0000x reference)
//
#include <hip/hip_runtime.h>
#include <hip/hip_bf16.h>

typedef __bf16 bf16_t;
typedef __bf16 bf16x8 __attribute__((ext_vector_type(8)));
typedef __bf16 bf16x4 __attribute__((ext_vector_type(4)));
typedef float  f32x4  __attribute__((ext_vector_type(4)));

#define NB  8
#define NC  256
#define NC8 32
#define NN  4096

#define MFMA16(a, b, c) __builtin_amdgcn_mfma_f32_16x16x32_bf16((a), (b), (c), 0, 0, 0)

// ---------------------------------------------------------------------------
// Kernel 0: fp32 -> bf16 elementwise (for weights). n4 = element_count/4.
// ---------------------------------------------------------------------------
__global__ __launch_bounds__(256) void cvt_f32_bf16(const float* __restrict__ in,
                                                    bf16_t* __restrict__ outb, int n4) {
    int i = blockIdx.x * 256 + threadIdx.x;
    if (i < n4) {
        float4 v = reinterpret_cast<const float4*>(in)[i];
        bf16x4 b;
        b[0] = (bf16_t)v.x; b[1] = (bf16_t)v.y; b[2] = (bf16_t)v.z; b[3] = (bf16_t)v.w;
        reinterpret_cast<bf16x4*>(outb)[i] = b;
    }
}

// ---------------------------------------------------------------------------
// Kernel 1: x fp32 [b][c][n] -> xt bf16 [b][n][c] (transpose + downconvert)
// ---------------------------------------------------------------------------
__global__ __launch_bounds__(256) void transpose_x(const float* __restrict__ x,
                                                   bf16_t* __restrict__ xt) {
    __shared__ bf16_t tile[64][72];  // [c_local][n_local], row stride 144B (16B mult)
    const int b  = blockIdx.z;
    const int c0 = blockIdx.y * 64;
    const int n0 = blockIdx.x * 64;
    const int t  = threadIdx.x;

    const int cl = t >> 4;          // 0..15
    const int nl = (t & 15) * 4;    // 0,4,..,60
    for (int p = 0; p < 4; ++p) {
        const int cc = cl + 16 * p;
        float4 v = *reinterpret_cast<const float4*>(
            x + ((size_t)b * NC + c0 + cc) * NN + n0 + nl);
        bf16x4 bv;
        bv[0] = (bf16_t)v.x; bv[1] = (bf16_t)v.y; bv[2] = (bf16_t)v.z; bv[3] = (bf16_t)v.w;
        *reinterpret_cast<bf16x4*>(&tile[cc][nl]) = bv;   // 144*cc + 8*(t&15): 8B aligned
    }
    __syncthreads();
    const int nb  = t >> 3;        // 0..31
    const int cl2 = (t & 7) * 8;
    for (int p = 0; p < 2; ++p) {
        const int nn = nb + 32 * p;
        bf16x8 v;
        for (int i = 0; i < 8; ++i) v[i] = tile[cl2 + i][nn];
        *reinterpret_cast<bf16x8*>(
            xt + ((size_t)b * NN + n0 + nn) * NC + c0 + cl2) = v;
    }
}

// ---------------------------------------------------------------------------
// Kernel 2: fused q/k projection (bf16 MFMA, fp32 bias).
//   ft[b][n][o] = sum_c xt[b][n][c]*wq[o][c] + bq[o]   (o<32), same for gt
// ---------------------------------------------------------------------------
__global__ __launch_bounds__(256) void proj_qk(const bf16_t* __restrict__ xt,
                                               const bf16_t* __restrict__ wq,
                                               const float* __restrict__ bq,
                                               const bf16_t* __restrict__ wk,
                                               const float* __restrict__ bk,
                                               bf16_t* __restrict__ ft,
                                               bf16_t* __restrict__ gt) {
    const int bx = blockIdx.x;
    const int b  = bx >> 6;
    const int n0 = (bx & 63) * 64;
    const int w    = threadIdx.x >> 6;
    const int lane = threadIdx.x & 63;
    const int q    = lane >> 4;
    const int r    = lane & 15;

    const bf16_t* xrow = xt + ((size_t)b * NN + n0 + 16 * w + r) * NC;

    f32x4 accq[2], acck[2];
    for (int ot = 0; ot < 2; ++ot) {
        accq[ot] = (f32x4){0.f, 0.f, 0.f, 0.f};
        acck[ot] = (f32x4){0.f, 0.f, 0.f, 0.f};
    }
    for (int k0 = 0; k0 < NC; k0 += 32) {
        bf16x8 a = *reinterpret_cast<const bf16x8*>(xrow + k0 + 8 * q);
        for (int ot = 0; ot < 2; ++ot) {
            bf16x8 fq = *reinterpret_cast<const bf16x8*>(wq + (size_t)(16 * ot + r) * NC + k0 + 8 * q);
            accq[ot] = MFMA16(a, fq, accq[ot]);
            bf16x8 fk = *reinterpret_cast<const bf16x8*>(wk + (size_t)(16 * ot + r) * NC + k0 + 8 * q);
            acck[ot] = MFMA16(a, fk, acck[ot]);
        }
    }
    // C-layout: row(n_loc) = 4q+reg, col(o) = r
    for (int ot = 0; ot < 2; ++ot) {
        const int o = 16 * ot + r;
        const float biq = bq[o];
        const float bik = bk[o];
        for (int i = 0; i < 4; ++i) {
            const int n = n0 + 16 * w + 4 * q + i;
            ft[((size_t)b * NN + n) * NC8 + o] = (bf16_t)(accq[ot][i] + biq);
            gt[((size_t)b * NN + n) * NC8 + o] = (bf16_t)(acck[ot][i] + bik);
        }
    }
}

// ---------------------------------------------------------------------------
// Kernel 3: v projection. h[b][c][n] = sum_k wv[c][k]*xt[b][n][k] + bv[c]
// ---------------------------------------------------------------------------
__global__ __launch_bounds__(256) void proj_v(const bf16_t* __restrict__ xt,
                                              const bf16_t* __restrict__ wv,
                                              const float* __restrict__ bv,
                                              bf16_t* __restrict__ h) {
    const int bx = blockIdx.x;            // 8 * 4 * 64
    const int b  = bx >> 8;
    const int ct0 = (bx >> 6) & 3;
    const int n0  = (bx & 63) * 64;
    const int c0  = ct0 * 64;
    const int w    = threadIdx.x >> 6;
    const int lane = threadIdx.x & 63;
    const int q    = lane >> 4;
    const int r    = lane & 15;

    f32x4 acc[4];
    for (int nt = 0; nt < 4; ++nt) acc[nt] = (f32x4){0.f, 0.f, 0.f, 0.f};

    const bf16_t* arow = wv + (size_t)(c0 + 16 * w + r) * NC;
    const bf16_t* xb   = xt + (size_t)b * NN * NC;
    for (int k0 = 0; k0 < NC; k0 += 32) {
        bf16x8 a = *reinterpret_cast<const bf16x8*>(arow + k0 + 8 * q);
        for (int nt = 0; nt < 4; ++nt) {
            bf16x8 bfrag = *reinterpret_cast<const bf16x8*>(
                xb + (size_t)(n0 + 16 * nt + r) * NC + k0 + 8 * q);
            acc[nt] = MFMA16(a, bfrag, acc[nt]);
        }
    }
    for (int nt = 0; nt < 4; ++nt) {
        for (int i = 0; i < 4; ++i) {
            const int c = c0 + 16 * w + 4 * q + i;
            const int n = n0 + 16 * nt + r;
            h[((size_t)b * NC + c) * NN + n] = (bf16_t)(acc[nt][i] + bv[c]);
        }
    }
}

// ---------------------------------------------------------------------------
// Kernel 4: attention. Block = (b, m-tile of 64). Loops n in 64-chunks:
//   S[n][m] = sum_c ft[n][c]*gt[m][c]  (c=32: one MFMA per 16x16 tile)
//   P = exp(S) -> LDS bf16 (no max subtraction: |s| < ~25, exp fits fp32)
//   O[c][m] += h[c][n-chunk] * P ; l[m] += col sums. Epilogue: out = O/l (fp32).
// ---------------------------------------------------------------------------
__global__ __launch_bounds__(256) void attn(const bf16_t* __restrict__ ft,
                                            const bf16_t* __restrict__ gt,
                                            const bf16_t* __restrict__ h,
                                            float* __restrict__ out) {
    __shared__ bf16_t P[64][72];   // row stride 144B = 16B multiple -> legal ds_read_b128
    __shared__ float  l_lds[64];

    const int bx = blockIdx.x;     // 8 * 64
    const int b  = bx >> 6;
    const int m0 = (bx & 63) * 64;
    const int tid  = threadIdx.x;
    const int w    = tid >> 6;
    const int lane = tid & 63;
    const int q    = lane >> 4;
    const int r    = lane & 15;

    if (tid < 64) l_lds[tid] = 0.f;

    // Q fragments (B-operand): gt[b][m0+16mt+r][8q..8q+7], resident all loop
    bf16x8 qf[4];
    for (int mt = 0; mt < 4; ++mt)
        qf[mt] = *reinterpret_cast<const bf16x8*>(
            gt + ((size_t)b * NN + m0 + 16 * mt + r) * NC8 + 8 * q);

    f32x4 acc[4][4];
    for (int ct = 0; ct < 4; ++ct)
        for (int mt = 0; mt < 4; ++mt) acc[ct][mt] = (f32x4){0.f, 0.f, 0.f, 0.f};
    float lp[4] = {0.f, 0.f, 0.f, 0.f};

    const bf16_t* fb = ft + (size_t)b * NN * NC8;
    const bf16_t* hb = h + (size_t)b * NC * NN;
    const f32x4 zero = (f32x4){0.f, 0.f, 0.f, 0.f};

    for (int n0 = 0; n0 < NN; n0 += 64) {
        // ---- S phase: wave w computes S rows [n0+16w, n0+16w+16) x 64 m
        bf16x8 af = *reinterpret_cast<const bf16x8*>(fb + (size_t)(n0 + 16 * w + r) * NC8 + 8 * q);
        f32x4 s[4];
        for (int mt = 0; mt < 4; ++mt) s[mt] = MFMA16(af, qf[mt], zero);

        __syncthreads();  // previous O-phase P reads complete
        for (int mt = 0; mt < 4; ++mt) {
            float e0 = __expf(s[mt][0]);
            float e1 = __expf(s[mt][1]);
            float e2 = __expf(s[mt][2]);
            float e3 = __expf(s[mt][3]);
            lp[mt] += (e0 + e1) + (e2 + e3);
            bf16x4 pv;
            pv[0] = (bf16_t)e0; pv[1] = (bf16_t)e1; pv[2] = (bf16_t)e2; pv[3] = (bf16_t)e3;
            // C-layout: row n_loc = 16w + 4q + reg, col m_loc = 16mt + r
            *reinterpret_cast<bf16x4*>(&P[16 * mt + r][16 * w + 4 * q]) = pv;
        }
        __syncthreads();

        // ---- O phase: wave w owns c in [64w, 64w+64)
        for (int half = 0; half < 2; ++half) {
            bf16x8 hf[4], pf[4];
            for (int ct = 0; ct < 4; ++ct)
                hf[ct] = *reinterpret_cast<const bf16x8*>(
                    hb + (size_t)(64 * w + 16 * ct + r) * NN + n0 + 32 * half + 8 * q);
            for (int mt = 0; mt < 4; ++mt)
                pf[mt] = *reinterpret_cast<const bf16x8*>(&P[16 * mt + r][32 * half + 8 * q]);
            for (int ct = 0; ct < 4; ++ct)
                for (int mt = 0; mt < 4; ++mt)
                    acc[ct][mt] = MFMA16(hf[ct], pf[mt], acc[ct][mt]);
        }
    }

    // ---- reduce l partials: sum over q groups (xor 16,32) then over waves
    __syncthreads();
    for (int mt = 0; mt < 4; ++mt) {
        float v = lp[mt];
        v += __shfl_xor(v, 16);
        v += __shfl_xor(v, 32);
        if (q == 0) atomicAdd(&l_lds[16 * mt + r], v);
    }
    __syncthreads();

    // ---- epilogue: out[b][c][m] = acc / l[m]  (fp32 output)
    for (int ct = 0; ct < 4; ++ct) {
        for (int mt = 0; mt < 4; ++mt) {
            const int m = m0 + 16 * mt + r;
            const float linv = 1.0f / l_lds[16 * mt + r];
            for (int i = 0; i < 4; ++i) {
                const int c = 64 * w + 16 * ct + 4 * q + i;
                out[((size_t)b * NC + c) * NN + m] = acc[ct][mt][i] * linv;
            }
        }
    }
}

extern "C" void kernel_launch(void* const* d_in, const int* in_sizes, int n_in,
                              void* d_out, int out_size, void* d_ws, size_t ws_size,
                              hipStream_t stream) {
    const float* x  = (const float*)d_in[0];
    const float* wq = (const float*)d_in[1];
    const float* bq = (const float*)d_in[2];
    const float* wk = (const float*)d_in[3];
    const float* bk = (const float*)d_in[4];
    const float* wv = (const float*)d_in[5];
    const float* bv = (const float*)d_in[6];
    float* out = (float*)d_out;

    bf16_t* xt  = (bf16_t*)d_ws;                     // [B][N][C]   16 MiB
    bf16_t* ft  = xt + (size_t)NB * NN * NC;         // [B][N][32]   2 MiB
    bf16_t* gt  = ft + (size_t)NB * NN * NC8;        // [B][N][32]   2 MiB
    bf16_t* hb  = gt + (size_t)NB * NN * NC8;        // [B][C][N]   16 MiB
    bf16_t* wqb = hb + (size_t)NB * NC * NN;         // [32][256]   16 KiB
    bf16_t* wkb = wqb + (size_t)NC8 * NC;            // [32][256]   16 KiB
    bf16_t* wvb = wkb + (size_t)NC8 * NC;            // [256][256] 128 KiB

    cvt_f32_bf16<<<(NC8 * NC / 4 + 255) / 256, 256, 0, stream>>>(wq, wqb, NC8 * NC / 4);
    cvt_f32_bf16<<<(NC8 * NC / 4 + 255) / 256, 256, 0, stream>>>(wk, wkb, NC8 * NC / 4);
    cvt_f32_bf16<<<(NC * NC / 4 + 255) / 256, 256, 0, stream>>>(wv, wvb, NC * NC / 4);
    transpose_x<<<dim3(NN / 64, NC / 64, NB), 256, 0, stream>>>(x, xt);
    proj_qk<<<NB * (NN / 64), 256, 0, stream>>>(xt, wqb, bq, wkb, bk, ft, gt);
    proj_v<<<NB * (NC / 64) * (NN / 64), 256, 0, stream>>>(xt, wvb, bv, hb);
    attn<<<NB * (NN / 64), 256, 0, stream>>>(ft, gt, hb, out);
}